// Round 13
// baseline (224.244 us; speedup 1.0000x reference)
//
#include <hip/hip_runtime.h>

constexpr int NN = 50000;   // nodes
constexpr int NE = 600000;  // edges
constexpr int D  = 128;     // features
constexpr int NR = 8;       // relations
constexpr int NSEG = NN * NR;        // 400000 (dst, rel) segments

constexpr int SCAN_ELEMS = 1024;
constexpr int NBLK2 = (NSEG + SCAN_ELEMS - 1) / SCAN_ELEMS;   // 391

constexpr int BM = 128;              // gemm row-tile; grid derives from THIS
constexpr int GEMM_GRID = (NN + BM - 1) / BM;   // 391

typedef unsigned int   u32;
typedef unsigned short u16;
typedef float  f32x4 __attribute__((ext_vector_type(4)));
typedef short  s16x8 __attribute__((ext_vector_type(8)));

__device__ __forceinline__ u16 f2bf(float f) {
    u32 u = __float_as_uint(f);
    u32 r = (u + 0x7fffu + ((u >> 16) & 1u)) >> 16;   // RNE
    return (u16)r;
}

__device__ __forceinline__ void async_cp16(const void* g, void* l) {
    __builtin_amdgcn_global_load_lds(
        (const __attribute__((address_space(1))) u32*)g,
        (__attribute__((address_space(3))) u32*)l, 16, 0, 0);
}

// ---------------- fused prep: count2 + convert_x + transpose_w -----------
// wt9 = 9 planes [col][k]: plane 0 = root^T, planes 1..8 = W_0..W_7^T
__global__ __launch_bounds__(256) void prep_all(const float* __restrict__ x,
                                                const float* __restrict__ weight,
                                                const float* __restrict__ root,
                                                const int* __restrict__ dst,
                                                const int* __restrict__ et,
                                                u16* __restrict__ xb,
                                                u16* __restrict__ wt9,
                                                int* __restrict__ cnt2) {
    const int NX4 = NN * D / 4;                 // 1.6M
    const int NW  = (NR + 1) * D * D;           // 147456
    int gid = blockIdx.x * 256 + threadIdx.x;
    if (gid < NX4) {
        int i = gid * 4;
        float4 v = *(const float4*)(x + i);
        ushort4 o;
        o.x = f2bf(v.x); o.y = f2bf(v.y); o.z = f2bf(v.z); o.w = f2bf(v.w);
        *(ushort4*)(xb + i) = o;
        return;
    }
    int g = gid - NX4;
    if (g < NW) {
        int p = g >> 14;          // plane 0..8
        int idx = g & 16383;      // n*128 + k  (n = output col)
        int n = idx >> 7, k = idx & 127;
        float v = (p == 0) ? root[k * D + n]
                           : weight[(size_t)(p - 1) * D * D + k * D + n];
        wt9[(size_t)p * 16384 + idx] = f2bf(v);
        return;
    }
    int e = g - NW;
    if (e < NE) atomicAdd(&cnt2[dst[e] * NR + et[e]], 1);
}

// ---------------- scans: exclusive scan of cnt2 -> offs2 -----------------
__global__ __launch_bounds__(256) void scan1(const int* __restrict__ cnt,
                                             int* __restrict__ offs,
                                             int* __restrict__ bsums) {
    __shared__ int lds[256];
    int t = threadIdx.x;
    int base = blockIdx.x * SCAN_ELEMS + t * 4;
    int v0 = (base + 0 < NSEG) ? cnt[base + 0] : 0;
    int v1 = (base + 1 < NSEG) ? cnt[base + 1] : 0;
    int v2 = (base + 2 < NSEG) ? cnt[base + 2] : 0;
    int v3 = (base + 3 < NSEG) ? cnt[base + 3] : 0;
    int s = v0 + v1 + v2 + v3;
    lds[t] = s;
    __syncthreads();
    int val = s;
    for (int off = 1; off < 256; off <<= 1) {
        int tmp = (t >= off) ? lds[t - off] : 0;
        __syncthreads();
        val += tmp;
        lds[t] = val;
        __syncthreads();
    }
    int ex = val - s;
    if (base + 0 < NSEG) offs[base + 0] = ex;
    if (base + 1 < NSEG) offs[base + 1] = ex + v0;
    if (base + 2 < NSEG) offs[base + 2] = ex + v0 + v1;
    if (base + 3 < NSEG) offs[base + 3] = ex + v0 + v1 + v2;
    if (t == 255) bsums[blockIdx.x] = val;
}

__global__ __launch_bounds__(512) void scan2(int* __restrict__ bsums) {
    __shared__ int lds[512];
    int t = threadIdx.x;
    int v = (t < NBLK2) ? bsums[t] : 0;
    lds[t] = v;
    __syncthreads();
    int val = v;
    for (int off = 1; off < 512; off <<= 1) {
        int tmp = (t >= off) ? lds[t - off] : 0;
        __syncthreads();
        val += tmp;
        lds[t] = val;
        __syncthreads();
    }
    if (t < NBLK2) bsums[t] = val - v;
}

__global__ __launch_bounds__(256) void scan3(int* __restrict__ offs,
                                             int* __restrict__ cur,
                                             const int* __restrict__ bsums) {
    int i = blockIdx.x * 256 + threadIdx.x;
    if (i < NSEG) {
        int v = offs[i] + bsums[i >> 10];
        offs[i] = v;
        cur[i]  = v;
    }
    if (i == 0) offs[NSEG] = NE;
}

// ---------------- bin edges by (dst, rel) --------------------------------
__global__ __launch_bounds__(256) void fill_bins(const int* __restrict__ src,
                                                 const int* __restrict__ dst,
                                                 const int* __restrict__ et,
                                                 int* __restrict__ cur,
                                                 int* __restrict__ ebin) {
    int e = blockIdx.x * 256 + threadIdx.x;
    if (e >= NE) return;
    int r = et[e];
    int idx = atomicAdd(&cur[dst[e] * NR + r], 1);
    ebin[idx] = (r << 16) | src[e];   // src < 50000 < 2^16
}

// ---------------- aggregation: relation-sorted, boundary-flush -----------
// r8-exact (plain stores — r11's nt stores were net negative for the
// pipeline: they perturbed the sums L3 hand-off to the gemm).
__global__ __launch_bounds__(128) void aggregate_kernel(const u32* __restrict__ xw,
                                                        const int* __restrict__ offs2,
                                                        const int* __restrict__ ebin,
                                                        u32* __restrict__ sw) {
    const int lane = threadIdx.x & 63;
    const int n = blockIdx.x * 2 + (threadIdx.x >> 6);
    if (n >= NN) return;
    const int beg = __builtin_amdgcn_readfirstlane(offs2[n * NR]);
    const int c   = __builtin_amdgcn_readfirstlane(offs2[n * NR + NR]) - beg;

    float a0 = 0.f, a1 = 0.f;
    int r_cur = 0, cnt_cur = 0;

    int q0 = 0, q1 = 0, q2 = 0, q3 = 0, q4 = 0, q5 = 0, q6 = 0, q7 = 0;
    u32 v0 = 0, v1 = 0, v2 = 0, v3 = 0, v4 = 0, v5 = 0, v6 = 0, v7 = 0;

#define REFILL(Q, V, IDX)                                                   \
    if ((IDX) < c) {                                                        \
        Q = __builtin_amdgcn_readfirstlane(ebin[beg + (IDX)]);              \
        V = xw[(size_t)((u32)Q & 0xffffu) * 64 + lane];                     \
    }
#define FLUSH()                                                             \
    {                                                                       \
        float inv_ = 1.0f / (float)(cnt_cur > 0 ? cnt_cur : 1);             \
        u32 lo16_ = f2bf(a0 * inv_);                                        \
        u32 hi16_ = f2bf(a1 * inv_);                                        \
        sw[((size_t)r_cur * NN + n) * 64 + lane] = lo16_ | (hi16_ << 16);   \
        a0 = 0.f; a1 = 0.f; cnt_cur = 0; ++r_cur;                           \
    }
#define CONSUME(Q, V)                                                       \
    {                                                                       \
        int rj_ = (int)((u32)(Q) >> 16);                                    \
        while (r_cur < rj_) FLUSH()                                         \
        a0 += __uint_as_float((V) << 16);                                   \
        a1 += __uint_as_float((V) & 0xffff0000u);                           \
        ++cnt_cur;                                                          \
    }

    REFILL(q0, v0, 0) REFILL(q1, v1, 1) REFILL(q2, v2, 2) REFILL(q3, v3, 3)
    REFILL(q4, v4, 4) REFILL(q5, v5, 5) REFILL(q6, v6, 6) REFILL(q7, v7, 7)

    int e = 0;
    for (; e + 8 <= c; e += 8) {
        CONSUME(q0, v0) REFILL(q0, v0, e + 8)
        CONSUME(q1, v1) REFILL(q1, v1, e + 9)
        CONSUME(q2, v2) REFILL(q2, v2, e + 10)
        CONSUME(q3, v3) REFILL(q3, v3, e + 11)
        CONSUME(q4, v4) REFILL(q4, v4, e + 12)
        CONSUME(q5, v5) REFILL(q5, v5, e + 13)
        CONSUME(q6, v6) REFILL(q6, v6, e + 14)
        CONSUME(q7, v7) REFILL(q7, v7, e + 15)
    }
    if (e + 0 < c) CONSUME(q0, v0)
    if (e + 1 < c) CONSUME(q1, v1)
    if (e + 2 < c) CONSUME(q2, v2)
    if (e + 3 < c) CONSUME(q3, v3)
    if (e + 4 < c) CONSUME(q4, v4)
    if (e + 5 < c) CONSUME(q5, v5)
    if (e + 6 < c) CONSUME(q6, v6)
    if (e + 7 < c) CONSUME(q7, v7)

    while (r_cur < NR) FLUSH()
#undef REFILL
#undef FLUSH
#undef CONSUME
}

// ---------------- fused MFMA GEMM: BM=128, BK=128, counted vmcnt ---------
// out[n][c] = relu( Σ_k A[n][k]*B[k][c] + bias[c] ), K = 1152.
// r12: BK 64 -> 128. One PLANE per iteration (9 iters; plane = it, kof=0).
// Rationale: five schedule variants all pinned at 41-43 us with nothing
// saturated -> bound by in-flight memory work per barrier window. BK=128
// doubles staged bytes in flight and halves the drain points (18 vs 36).
// A: direct global->VGPR, depth-1 prefetch (iter is 2x longer; 8 frags).
// B: shared dbuf LDS (2x32 KB = 64 KB; grid-limited 1.5 blk/CU so free).
//    XOR swizzle for [col][k128] panel: g = col*16+j, p = g ^ ((g>>4)&7)
//    — involution, col-preserving, both sides (source + ds_read).
// vmcnt: per iter issues S(it+1)=8 + A(it+1)=8 -> vmcnt(16) proves
//    S(it)+A(it) retired. Final tile vmcnt(0).
__global__ __launch_bounds__(256) void mfma_gemm(const u16* __restrict__ xb,
                                                 const u16* __restrict__ sums,
                                                 const u16* __restrict__ wt9,
                                                 const float* __restrict__ bias,
                                                 float* __restrict__ out) {
    __shared__ __align__(16) u16 Bs[2][128 * 128];   // 64 KB

    const int tid  = threadIdx.x;
    const int wave = tid >> 6;
    const int lane = tid & 63;
    const int m0   = blockIdx.x * BM;
    const int fr   = lane & 15;
    const int l4   = lane >> 4;          // 0..3

    // stage mapping: 2048 granules of 16B per buffer, 8 rounds x 256 thr.
    // physical p <- logical g = p ^ ((p>>4)&7); g = col*16 + j (j = 0..15)
    int boff[8];
#pragma unroll
    for (int r = 0; r < 8; ++r) {
        int p = r * 256 + tid;
        int g = p ^ ((p >> 4) & 7);
        boff[r] = (g >> 4) * 128 + (g & 15) * 8;   // u16 offset in [col][k] panel
    }
    // read mapping: frag (kc,nt): g = (nt*16+fr)*16 + kc*4 + l4
    int bidx[32];
#pragma unroll
    for (int kc = 0; kc < 4; ++kc)
#pragma unroll
        for (int nt = 0; nt < 8; ++nt) {
            int gl = (nt * 16 + fr) * 16 + kc * 4 + l4;
            int pp = gl ^ ((gl >> 4) & 7);
            bidx[kc * 8 + nt] = pp * 8;             // u16 index
        }

    int r0 = m0 + wave * 32 + fr;       if (r0 > NN - 1) r0 = NN - 1;
    int r1 = m0 + wave * 32 + 16 + fr;  if (r1 > NN - 1) r1 = NN - 1;
    const size_t aoff0 = (size_t)r0 * D + l4 * 8;
    const size_t aoff1 = (size_t)r1 * D + l4 * 8;

    auto stage = [&](u16* bufp, const u16* Bp) {
#pragma unroll
        for (int r = 0; r < 8; ++r)
            async_cp16(Bp + boff[r], (char*)bufp + (size_t)(r * 256 + tid) * 16);
    };

    f32x4 acc0[8], acc1[8];
#pragma unroll
    for (int j = 0; j < 8; ++j) {
        acc0[j] = (f32x4){0.f, 0.f, 0.f, 0.f};
        acc1[j] = (f32x4){0.f, 0.f, 0.f, 0.f};
    }

    // A frags: ac = iter it (8: rowgrp0 kc0..3, rowgrp1 kc0..3), an = it+1.
    // Only accessed in fully-unrolled loops -> static indexing.
    s16x8 ac[8], an[8];

    // prologue: S(0) = plane 0 (root), A(0) from xb
    stage(&Bs[0][0], wt9);
#pragma unroll
    for (int kc = 0; kc < 4; ++kc) {
        ac[kc]     = *(const s16x8*)(xb + aoff0 + kc * 32);
        ac[4 + kc] = *(const s16x8*)(xb + aoff1 + kc * 32);
    }
    __builtin_amdgcn_sched_barrier(0);   // pin prologue VMEM group (FIFO count)

    for (int it = 0; it < 8; ++it) {
        // S(it+1): plane it+1; A(it+1): sums plane it (= plane (it+1)-1)
        stage(&Bs[(it + 1) & 1][0], wt9 + (size_t)(it + 1) * 16384);
        const u16* Ap = sums + (size_t)it * NN * D;
#pragma unroll
        for (int kc = 0; kc < 4; ++kc) {
            an[kc]     = *(const s16x8*)(Ap + aoff0 + kc * 32);
            an[4 + kc] = *(const s16x8*)(Ap + aoff1 + kc * 32);
        }
        __builtin_amdgcn_sched_barrier(0);
        asm volatile("s_waitcnt vmcnt(16)" ::: "memory");  // S(it)+A(it) retired
        __builtin_amdgcn_s_barrier();                      // all waves: cbuf ready
        __builtin_amdgcn_sched_barrier(0);                 // no ds_read hoists above
        const u16* cbuf = &Bs[it & 1][0];
#pragma unroll
        for (int kc = 0; kc < 4; ++kc) {
#pragma unroll
            for (int nt = 0; nt < 8; ++nt) {
                s16x8 bf = *(const s16x8*)(cbuf + bidx[kc * 8 + nt]);
                acc0[nt] = __builtin_amdgcn_mfma_f32_16x16x32_bf16(ac[kc],     bf, acc0[nt], 0, 0, 0);
                acc1[nt] = __builtin_amdgcn_mfma_f32_16x16x32_bf16(ac[4 + kc], bf, acc1[nt], 0, 0, 0);
            }
        }
        asm volatile("s_waitcnt lgkmcnt(0)" ::: "memory"); // reads of cbuf done
        __builtin_amdgcn_sched_barrier(0);
        __builtin_amdgcn_s_barrier();                      // WAR guard
        __builtin_amdgcn_sched_barrier(0);                 // no next-stage hoists
#pragma unroll
        for (int j = 0; j < 8; ++j) ac[j] = an[j];         // rotate A
    }
    // final iteration (it=8, plane 8, buffer Bs[0]): full drain ok
    asm volatile("s_waitcnt vmcnt(0)" ::: "memory");
    __builtin_amdgcn_s_barrier();
    __builtin_amdgcn_sched_barrier(0);
    {
        const u16* cbuf = &Bs[0][0];
#pragma unroll
        for (int kc = 0; kc < 4; ++kc) {
#pragma unroll
            for (int nt = 0; nt < 8; ++nt) {
                s16x8 bf = *(const s16x8*)(cbuf + bidx[kc * 8 + nt]);
                acc0[nt] = __builtin_amdgcn_mfma_f32_16x16x32_bf16(ac[kc],     bf, acc0[nt], 0, 0, 0);
                acc1[nt] = __builtin_amdgcn_mfma_f32_16x16x32_bf16(ac[4 + kc], bf, acc1[nt], 0, 0, 0);
            }
        }
    }

    // epilogue: C/D layout col=lane&15, row=(lane>>4)*4+reg; 2 row-groups
    const int cl = lane & 15;
    const int rq = l4 * 4;
#pragma unroll
    for (int nt = 0; nt < 8; ++nt) {
        int col = nt * 16 + cl;
        float bv = bias[col];
#pragma unroll
        for (int reg = 0; reg < 4; ++reg) {
            int n = m0 + wave * 32 + rq + reg;
            if (n < NN) {
                float v = acc0[nt][reg] + bv;
                out[(size_t)n * D + col] = fmaxf(v, 0.0f);
            }
            int n2 = n + 16;
            if (n2 < NN) {
                float v = acc1[nt][reg] + bv;
                out[(size_t)n2 * D + col] = fmaxf(v, 0.0f);
            }
        }
    }
}

extern "C" void kernel_launch(void* const* d_in, const int* in_sizes, int n_in,
                              void* d_out, int out_size, void* d_ws, size_t ws_size,
                              hipStream_t stream) {
    const float* x      = (const float*)d_in[0];
    const int*   ei     = (const int*)d_in[1];
    const int*   et     = (const int*)d_in[2];
    const float* weight = (const float*)d_in[3];
    const float* root   = (const float*)d_in[4];
    const float* bias   = (const float*)d_in[5];
    float* out = (float*)d_out;
    const int* srcv = ei;
    const int* dstv = ei + NE;

    // ws: ints [cnt2 NSEG][cur2 NSEG][offs2 NSEG+1][bsums 512][ebin NE],
    // then u16 [xb NN*D][sums NR*NN*D][wt9 9*D*D]
    int* cnt2  = (int*)d_ws;
    int* cur2  = cnt2 + NSEG;
    int* offs2 = cur2 + NSEG;
    int* bsums = offs2 + NSEG + 1;
    int* ebin  = bsums + 512;
    size_t fixed_b  = ((char*)(ebin + NE) - (char*)d_ws);
    size_t fixed_al = (fixed_b + 255) & ~(size_t)255;
    u16* xb   = (u16*)((char*)d_ws + fixed_al);
    u16* sums = xb + (size_t)NN * D;
    u16* wt9  = sums + (size_t)NR * NN * D;

    (void)hipMemsetAsync(cnt2, 0, NSEG * sizeof(int), stream);

    const int PREP = NN * D / 4 + (NR + 1) * D * D + NE;
    prep_all<<<(PREP + 255) / 256, 256, 0, stream>>>(x, weight, root, dstv, et,
                                                     xb, wt9, cnt2);

    scan1<<<NBLK2, 256, 0, stream>>>(cnt2, offs2, bsums);
    scan2<<<1, 512, 0, stream>>>(bsums);
    scan3<<<(NSEG + 256) / 256, 256, 0, stream>>>(offs2, cur2, bsums);
    fill_bins<<<(NE + 255) / 256, 256, 0, stream>>>(srcv, dstv, et, cur2, ebin);

    aggregate_kernel<<<(NN + 1) / 2, 128, 0, stream>>>((const u32*)xb, offs2, ebin,
                                                       (u32*)sums);

    mfma_gemm<<<GEMM_GRID, 256, 0, stream>>>(xb, sums, wt9, bias, out);
}

// Round 14
// 216.104 us; speedup vs baseline: 1.0377x; 1.0377x over previous
//
#include <hip/hip_runtime.h>

constexpr int NN = 50000;   // nodes
constexpr int NE = 600000;  // edges
constexpr int D  = 128;     // features
constexpr int NR = 8;       // relations
constexpr int NSEG = NN * NR;        // 400000 (dst, rel) segments

constexpr int SCAN_ELEMS = 1024;
constexpr int NBLK2 = (NSEG + SCAN_ELEMS - 1) / SCAN_ELEMS;   // 391

constexpr int BM = 128;              // gemm row-tile; grid derives from THIS
constexpr int GEMM_GRID = (NN + BM - 1) / BM;   // 391

typedef unsigned int   u32;
typedef unsigned short u16;
typedef float  f32x4 __attribute__((ext_vector_type(4)));
typedef short  s16x8 __attribute__((ext_vector_type(8)));

__device__ __forceinline__ u16 f2bf(float f) {
    u32 u = __float_as_uint(f);
    u32 r = (u + 0x7fffu + ((u >> 16) & 1u)) >> 16;   // RNE
    return (u16)r;
}

__device__ __forceinline__ void async_cp16(const void* g, void* l) {
    __builtin_amdgcn_global_load_lds(
        (const __attribute__((address_space(1))) u32*)g,
        (__attribute__((address_space(3))) u32*)l, 16, 0, 0);
}

// ---------------- fused prep: count2 + convert_x + transpose_w -----------
// wt9 = 9 planes [col][k]: plane 0 = root^T, planes 1..8 = W_0..W_7^T
__global__ __launch_bounds__(256) void prep_all(const float* __restrict__ x,
                                                const float* __restrict__ weight,
                                                const float* __restrict__ root,
                                                const int* __restrict__ dst,
                                                const int* __restrict__ et,
                                                u16* __restrict__ xb,
                                                u16* __restrict__ wt9,
                                                int* __restrict__ cnt2) {
    const int NX4 = NN * D / 4;                 // 1.6M
    const int NW  = (NR + 1) * D * D;           // 147456
    int gid = blockIdx.x * 256 + threadIdx.x;
    if (gid < NX4) {
        int i = gid * 4;
        float4 v = *(const float4*)(x + i);
        ushort4 o;
        o.x = f2bf(v.x); o.y = f2bf(v.y); o.z = f2bf(v.z); o.w = f2bf(v.w);
        *(ushort4*)(xb + i) = o;
        return;
    }
    int g = gid - NX4;
    if (g < NW) {
        int p = g >> 14;          // plane 0..8
        int idx = g & 16383;      // n*128 + k  (n = output col)
        int n = idx >> 7, k = idx & 127;
        float v = (p == 0) ? root[k * D + n]
                           : weight[(size_t)(p - 1) * D * D + k * D + n];
        wt9[(size_t)p * 16384 + idx] = f2bf(v);
        return;
    }
    int e = g - NW;
    if (e < NE) atomicAdd(&cnt2[dst[e] * NR + et[e]], 1);
}

// ---------------- scans: exclusive scan of cnt2 -> offs2 -----------------
__global__ __launch_bounds__(256) void scan1(const int* __restrict__ cnt,
                                             int* __restrict__ offs,
                                             int* __restrict__ bsums) {
    __shared__ int lds[256];
    int t = threadIdx.x;
    int base = blockIdx.x * SCAN_ELEMS + t * 4;
    int v0 = (base + 0 < NSEG) ? cnt[base + 0] : 0;
    int v1 = (base + 1 < NSEG) ? cnt[base + 1] : 0;
    int v2 = (base + 2 < NSEG) ? cnt[base + 2] : 0;
    int v3 = (base + 3 < NSEG) ? cnt[base + 3] : 0;
    int s = v0 + v1 + v2 + v3;
    lds[t] = s;
    __syncthreads();
    int val = s;
    for (int off = 1; off < 256; off <<= 1) {
        int tmp = (t >= off) ? lds[t - off] : 0;
        __syncthreads();
        val += tmp;
        lds[t] = val;
        __syncthreads();
    }
    int ex = val - s;
    if (base + 0 < NSEG) offs[base + 0] = ex;
    if (base + 1 < NSEG) offs[base + 1] = ex + v0;
    if (base + 2 < NSEG) offs[base + 2] = ex + v0 + v1;
    if (base + 3 < NSEG) offs[base + 3] = ex + v0 + v1 + v2;
    if (t == 255) bsums[blockIdx.x] = val;
}

__global__ __launch_bounds__(512) void scan2(int* __restrict__ bsums) {
    __shared__ int lds[512];
    int t = threadIdx.x;
    int v = (t < NBLK2) ? bsums[t] : 0;
    lds[t] = v;
    __syncthreads();
    int val = v;
    for (int off = 1; off < 512; off <<= 1) {
        int tmp = (t >= off) ? lds[t - off] : 0;
        __syncthreads();
        val += tmp;
        lds[t] = val;
        __syncthreads();
    }
    if (t < NBLK2) bsums[t] = val - v;
}

__global__ __launch_bounds__(256) void scan3(int* __restrict__ offs,
                                             int* __restrict__ cur,
                                             const int* __restrict__ bsums) {
    int i = blockIdx.x * 256 + threadIdx.x;
    if (i < NSEG) {
        int v = offs[i] + bsums[i >> 10];
        offs[i] = v;
        cur[i]  = v;
    }
    if (i == 0) offs[NSEG] = NE;
}

// ---------------- bin edges by (dst, rel) --------------------------------
__global__ __launch_bounds__(256) void fill_bins(const int* __restrict__ src,
                                                 const int* __restrict__ dst,
                                                 const int* __restrict__ et,
                                                 int* __restrict__ cur,
                                                 int* __restrict__ ebin) {
    int e = blockIdx.x * 256 + threadIdx.x;
    if (e >= NE) return;
    int r = et[e];
    int idx = atomicAdd(&cur[dst[e] * NR + r], 1);
    ebin[idx] = (r << 16) | src[e];   // src < 50000 < 2^16
}

// ---------------- aggregation: relation-sorted, boundary-flush -----------
// r14: empty segments (cnt_cur==0, ~22% of 400K) skip the store entirely
// (wave-uniform branch). The gemm redirects those A-loads to a zero page.
// Saves ~22.8 MB of the 102.4 MB write stream.
__global__ __launch_bounds__(128) void aggregate_kernel(const u32* __restrict__ xw,
                                                        const int* __restrict__ offs2,
                                                        const int* __restrict__ ebin,
                                                        u32* __restrict__ sw) {
    const int lane = threadIdx.x & 63;
    const int n = blockIdx.x * 2 + (threadIdx.x >> 6);
    if (n >= NN) return;
    const int beg = __builtin_amdgcn_readfirstlane(offs2[n * NR]);
    const int c   = __builtin_amdgcn_readfirstlane(offs2[n * NR + NR]) - beg;

    float a0 = 0.f, a1 = 0.f;
    int r_cur = 0, cnt_cur = 0;

    int q0 = 0, q1 = 0, q2 = 0, q3 = 0, q4 = 0, q5 = 0, q6 = 0, q7 = 0;
    u32 v0 = 0, v1 = 0, v2 = 0, v3 = 0, v4 = 0, v5 = 0, v6 = 0, v7 = 0;

#define REFILL(Q, V, IDX)                                                   \
    if ((IDX) < c) {                                                        \
        Q = __builtin_amdgcn_readfirstlane(ebin[beg + (IDX)]);              \
        V = xw[(size_t)((u32)Q & 0xffffu) * 64 + lane];                     \
    }
#define FLUSH()                                                             \
    {                                                                       \
        if (cnt_cur > 0) {                                                  \
            float inv_ = 1.0f / (float)cnt_cur;                             \
            u32 lo16_ = f2bf(a0 * inv_);                                    \
            u32 hi16_ = f2bf(a1 * inv_);                                    \
            sw[((size_t)r_cur * NN + n) * 64 + lane] = lo16_ | (hi16_ << 16);\
            a0 = 0.f; a1 = 0.f; cnt_cur = 0;                                \
        }                                                                   \
        ++r_cur;                                                            \
    }
#define CONSUME(Q, V)                                                       \
    {                                                                       \
        int rj_ = (int)((u32)(Q) >> 16);                                    \
        while (r_cur < rj_) FLUSH()                                         \
        a0 += __uint_as_float((V) << 16);                                   \
        a1 += __uint_as_float((V) & 0xffff0000u);                           \
        ++cnt_cur;                                                          \
    }

    REFILL(q0, v0, 0) REFILL(q1, v1, 1) REFILL(q2, v2, 2) REFILL(q3, v3, 3)
    REFILL(q4, v4, 4) REFILL(q5, v5, 5) REFILL(q6, v6, 6) REFILL(q7, v7, 7)

    int e = 0;
    for (; e + 8 <= c; e += 8) {
        CONSUME(q0, v0) REFILL(q0, v0, e + 8)
        CONSUME(q1, v1) REFILL(q1, v1, e + 9)
        CONSUME(q2, v2) REFILL(q2, v2, e + 10)
        CONSUME(q3, v3) REFILL(q3, v3, e + 11)
        CONSUME(q4, v4) REFILL(q4, v4, e + 12)
        CONSUME(q5, v5) REFILL(q5, v5, e + 13)
        CONSUME(q6, v6) REFILL(q6, v6, e + 14)
        CONSUME(q7, v7) REFILL(q7, v7, e + 15)
    }
    if (e + 0 < c) CONSUME(q0, v0)
    if (e + 1 < c) CONSUME(q1, v1)
    if (e + 2 < c) CONSUME(q2, v2)
    if (e + 3 < c) CONSUME(q3, v3)
    if (e + 4 < c) CONSUME(q4, v4)
    if (e + 5 < c) CONSUME(q5, v5)
    if (e + 6 < c) CONSUME(q6, v6)
    if (e + 7 < c) CONSUME(q7, v7)

    while (r_cur < NR) FLUSH()
#undef REFILL
#undef FLUSH
#undef CONSUME
}

// ---------------- fused MFMA GEMM: BM=128, BK=64 (r8) + empty-redirect ---
// out[n][c] = relu( Σ_k A[n][k]*B[k][c] + bias[c] ), K = 1152, BK = 64.
// r8-exact schedule (verified 215.8 us total). r14 adds: per-lane empty
// bitmaps from offs2 (6 prologue loads, consumed BEFORE the pinned VMEM
// groups -> FIFO vmcnt accounting unchanged); empty (row,rel) A-loads are
// address-redirected to a zeroed 512B page (L2-hot broadcast). Address
// select happens pre-load -> no data dependency, no extra stalls, load
// count per group unchanged -> vmcnt(12)/(8) derivation identical to r8.
// Inside the loop p2 = (it+2)>>1 >= 1 always, so all loop A-loads are
// sums-loads (xb only in prologue, never empty).
__global__ __launch_bounds__(256) void mfma_gemm(const u16* __restrict__ xb,
                                                 const u16* __restrict__ sums,
                                                 const u16* __restrict__ wt9,
                                                 const float* __restrict__ bias,
                                                 const int* __restrict__ offs2,
                                                 const u16* __restrict__ zp,
                                                 float* __restrict__ out) {
    __shared__ __align__(16) u16 Bs[2][128 * 64];   // 32 KB

    const int tid  = threadIdx.x;
    const int wave = tid >> 6;
    const int lane = tid & 63;
    const int m0   = blockIdx.x * BM;
    const int fr   = lane & 15;
    const int l4   = lane >> 4;          // 0..3
    const int fk   = l4 * 8;

    int boff[4];
#pragma unroll
    for (int r = 0; r < 4; ++r) {
        int p = r * 256 + tid;
        int g = p ^ ((p >> 3) & 7);
        boff[r] = (g >> 3) * D + (g & 7) * 8;     // u16 offset in [col][k] panel
    }
    int bidx[16];
#pragma unroll
    for (int h = 0; h < 2; ++h)
#pragma unroll
        for (int nt = 0; nt < 8; ++nt) {
            int gl = (nt * 16 + fr) * 8 + h * 4 + l4;
            int pp = gl ^ ((gl >> 3) & 7);
            bidx[h * 8 + nt] = pp * 8;             // u16 index
        }

    int r0 = m0 + wave * 32 + fr;       if (r0 > NN - 1) r0 = NN - 1;
    int r1 = m0 + wave * 32 + 16 + fr;  if (r1 > NN - 1) r1 = NN - 1;
    const size_t aoff0 = (size_t)r0 * D + fk;
    const size_t aoff1 = (size_t)r1 * D + fk;

    // ---- empty bitmaps (bit r = segment (row, r) empty), prologue-only --
    // 6 vector loads, fully consumed here -> retired before the pinned
    // staging groups; vmcnt FIFO counts below are unaffected.
    u32 emp0, emp1;
    {
        const int* q0 = offs2 + r0 * NR;
        int4 A0 = *(const int4*)q0;
        int4 B0 = *(const int4*)(q0 + 4);
        int  C0 = q0[8];
        emp0 = (u32)(A0.y == A0.x) | ((u32)(A0.z == A0.y) << 1) |
               ((u32)(A0.w == A0.z) << 2) | ((u32)(B0.x == A0.w) << 3) |
               ((u32)(B0.y == B0.x) << 4) | ((u32)(B0.z == B0.y) << 5) |
               ((u32)(B0.w == B0.z) << 6) | ((u32)(C0 == B0.w) << 7);
        const int* q1 = offs2 + r1 * NR;
        int4 A1 = *(const int4*)q1;
        int4 B1 = *(const int4*)(q1 + 4);
        int  C1 = q1[8];
        emp1 = (u32)(A1.y == A1.x) | ((u32)(A1.z == A1.y) << 1) |
               ((u32)(A1.w == A1.z) << 2) | ((u32)(B1.x == A1.w) << 3) |
               ((u32)(B1.y == B1.x) << 4) | ((u32)(B1.z == B1.y) << 5) |
               ((u32)(B1.w == B1.z) << 6) | ((u32)(C1 == B1.w) << 7);
    }
    __builtin_amdgcn_sched_barrier(0);   // mask loads retired; clean FIFO

    auto stage = [&](u16* bufp, const u16* Bp) {
#pragma unroll
        for (int r = 0; r < 4; ++r)
            async_cp16(Bp + boff[r], (char*)bufp + (size_t)(r * 256 + tid) * 16);
    };

    f32x4 acc0[8], acc1[8];
#pragma unroll
    for (int j = 0; j < 8; ++j) {
        acc0[j] = (f32x4){0.f, 0.f, 0.f, 0.f};
        acc1[j] = (f32x4){0.f, 0.f, 0.f, 0.f};
    }

    s16x8 a0c, a1c, a2c, a3c, a0n1, a1n1, a2n1, a3n1, a0n2, a1n2, a2n2, a3n2;

    // K-plan: 18 iters of BK=64; plane = it>>1 (0 = root/xb), kof = (it&1)*64
    stage(&Bs[0][0], wt9);
    a0c  = *(const s16x8*)(xb + aoff0);          // A(0), kof 0
    a1c  = *(const s16x8*)(xb + aoff0 + 32);
    a2c  = *(const s16x8*)(xb + aoff1);
    a3c  = *(const s16x8*)(xb + aoff1 + 32);
    a0n1 = *(const s16x8*)(xb + aoff0 + 64);     // A(1), kof 64
    a1n1 = *(const s16x8*)(xb + aoff0 + 96);
    a2n1 = *(const s16x8*)(xb + aoff1 + 64);
    a3n1 = *(const s16x8*)(xb + aoff1 + 96);
    a0n2 = a0n1; a1n2 = a1n1; a2n2 = a2n1; a3n2 = a3n1;
    __builtin_amdgcn_sched_barrier(0);   // pin prologue VMEM group (FIFO count)

    for (int it = 0; it < 17; ++it) {
        const int nx  = it + 1;
        const int npl = nx >> 1;
        const int kof = (nx & 1) * 64;
        u16* nbuf = &Bs[nx & 1][0];
        const u16* cbuf = &Bs[it & 1][0];

        stage(nbuf, wt9 + npl * 16384 + kof);          // S(it+1): 4 cp16
        if (it + 2 <= 17) {                            // A(it+2): 4 loads
            const int p2 = (it + 2) >> 1;              // 1..8 inside loop
            const int k2 = ((it + 2) & 1) * 64;
            const int rel = p2 - 1;
            const u16* Ap2 = sums + (size_t)rel * NN * D + k2;
            const u16* b0 = ((emp0 >> rel) & 1) ? zp : Ap2 + aoff0;
            const u16* b1 = ((emp1 >> rel) & 1) ? zp : Ap2 + aoff1;
            a0n2 = *(const s16x8*)(b0);
            a1n2 = *(const s16x8*)(b0 + 32);
            a2n2 = *(const s16x8*)(b1);
            a3n2 = *(const s16x8*)(b1 + 32);
        }
        __builtin_amdgcn_sched_barrier(0);
        if (it < 16) { asm volatile("s_waitcnt vmcnt(12)" ::: "memory"); }
        else         { asm volatile("s_waitcnt vmcnt(8)"  ::: "memory"); }
        __builtin_amdgcn_s_barrier();                  // all waves: cbuf ready
        __builtin_amdgcn_sched_barrier(0);             // no ds_read hoists above
#pragma unroll
        for (int nt = 0; nt < 8; ++nt) {               // khalf 0: 1 read, 2 MFMA
            s16x8 bf = *(const s16x8*)(cbuf + bidx[nt]);
            acc0[nt] = __builtin_amdgcn_mfma_f32_16x16x32_bf16(a0c, bf, acc0[nt], 0, 0, 0);
            acc1[nt] = __builtin_amdgcn_mfma_f32_16x16x32_bf16(a2c, bf, acc1[nt], 0, 0, 0);
        }
#pragma unroll
        for (int nt = 0; nt < 8; ++nt) {               // khalf 1
            s16x8 bf = *(const s16x8*)(cbuf + bidx[8 + nt]);
            acc0[nt] = __builtin_amdgcn_mfma_f32_16x16x32_bf16(a1c, bf, acc0[nt], 0, 0, 0);
            acc1[nt] = __builtin_amdgcn_mfma_f32_16x16x32_bf16(a3c, bf, acc1[nt], 0, 0, 0);
        }
        asm volatile("s_waitcnt lgkmcnt(0)" ::: "memory"); // reads of cbuf done
        __builtin_amdgcn_sched_barrier(0);
        __builtin_amdgcn_s_barrier();                      // WAR guard
        __builtin_amdgcn_sched_barrier(0);                 // no next-stage hoists
        a0c = a0n1; a1c = a1n1; a2c = a2n1; a3c = a3n1;    // rotate A queue
        a0n1 = a0n2; a1n1 = a1n2; a2n1 = a2n2; a3n1 = a3n2;
    }
    // final tile (it=17, buffer 1): full drain ok
    asm volatile("s_waitcnt vmcnt(0)" ::: "memory");
    __builtin_amdgcn_s_barrier();
    __builtin_amdgcn_sched_barrier(0);
    {
        const u16* cbuf = &Bs[1][0];
#pragma unroll
        for (int nt = 0; nt < 8; ++nt) {
            s16x8 bf = *(const s16x8*)(cbuf + bidx[nt]);
            acc0[nt] = __builtin_amdgcn_mfma_f32_16x16x32_bf16(a0c, bf, acc0[nt], 0, 0, 0);
            acc1[nt] = __builtin_amdgcn_mfma_f32_16x16x32_bf16(a2c, bf, acc1[nt], 0, 0, 0);
        }
#pragma unroll
        for (int nt = 0; nt < 8; ++nt) {
            s16x8 bf = *(const s16x8*)(cbuf + bidx[8 + nt]);
            acc0[nt] = __builtin_amdgcn_mfma_f32_16x16x32_bf16(a1c, bf, acc0[nt], 0, 0, 0);
            acc1[nt] = __builtin_amdgcn_mfma_f32_16x16x32_bf16(a3c, bf, acc1[nt], 0, 0, 0);
        }
    }

    // epilogue: C/D layout col=lane&15, row=(lane>>4)*4+reg; 2 row-groups
    const int cl = lane & 15;
    const int rq = l4 * 4;
#pragma unroll
    for (int nt = 0; nt < 8; ++nt) {
        int col = nt * 16 + cl;
        float bv = bias[col];
#pragma unroll
        for (int reg = 0; reg < 4; ++reg) {
            int n = m0 + wave * 32 + rq + reg;
            if (n < NN) {
                float v = acc0[nt][reg] + bv;
                out[(size_t)n * D + col] = fmaxf(v, 0.0f);
            }
            int n2 = n + 16;
            if (n2 < NN) {
                float v = acc1[nt][reg] + bv;
                out[(size_t)n2 * D + col] = fmaxf(v, 0.0f);
            }
        }
    }
}

extern "C" void kernel_launch(void* const* d_in, const int* in_sizes, int n_in,
                              void* d_out, int out_size, void* d_ws, size_t ws_size,
                              hipStream_t stream) {
    const float* x      = (const float*)d_in[0];
    const int*   ei     = (const int*)d_in[1];
    const int*   et     = (const int*)d_in[2];
    const float* weight = (const float*)d_in[3];
    const float* root   = (const float*)d_in[4];
    const float* bias   = (const float*)d_in[5];
    float* out = (float*)d_out;
    const int* srcv = ei;
    const int* dstv = ei + NE;

    // ws: ints [cnt2 NSEG][zp 128][cur2 NSEG][offs2 NSEG+1][bsums 512]
    //     [ebin NE], then u16 [xb NN*D][sums NR*NN*D][wt9 9*D*D]
    int* cnt2  = (int*)d_ws;
    int* zpi   = cnt2 + NSEG;            // 512 B zero page (memset'd)
    int* cur2  = zpi + 128;
    int* offs2 = cur2 + NSEG;
    int* bsums = offs2 + NSEG + 1;
    int* ebin  = bsums + 512;
    size_t fixed_b  = ((char*)(ebin + NE) - (char*)d_ws);
    size_t fixed_al = (fixed_b + 255) & ~(size_t)255;
    u16* xb   = (u16*)((char*)d_ws + fixed_al);
    u16* sums = xb + (size_t)NN * D;
    u16* wt9  = sums + (size_t)NR * NN * D;

    // one memset covers cnt2 AND the zero page (contiguous)
    (void)hipMemsetAsync(cnt2, 0, (NSEG + 128) * sizeof(int), stream);

    const int PREP = NN * D / 4 + (NR + 1) * D * D + NE;
    prep_all<<<(PREP + 255) / 256, 256, 0, stream>>>(x, weight, root, dstv, et,
                                                     xb, wt9, cnt2);

    scan1<<<NBLK2, 256, 0, stream>>>(cnt2, offs2, bsums);
    scan2<<<1, 512, 0, stream>>>(bsums);
    scan3<<<(NSEG + 256) / 256, 256, 0, stream>>>(offs2, cur2, bsums);
    fill_bins<<<(NE + 255) / 256, 256, 0, stream>>>(srcv, dstv, et, cur2, ebin);

    aggregate_kernel<<<(NN + 1) / 2, 128, 0, stream>>>((const u32*)xb, offs2, ebin,
                                                       (u32*)sums);

    mfma_gemm<<<GEMM_GRID, 256, 0, stream>>>(xb, sums, wt9, bias, offs2,
                                             (const u16*)zpi, out);
}